// Round 7
// baseline (73203.857 us; speedup 1.0000x reference)
//
#include <hip/hip_runtime.h>

// LureSystem recurrence, MI355X.
// R7: explicit AGPR pinning. R2..R6 established: (1) the 64-VGPR budget is
// immovable via attributes (5 configs, identical codegen); (2) with 64 VGPRs
// the compiler keeps ~1 of 3 weight matrices register-resident and re-reads
// the other two from memory every step (22 GB FETCH = entire 23 ms runtime).
// Fix: gfx950 unified RF + zero MFMA usage => AGPRs are free. Pin all 192
// per-thread weight packs (C2/A/B2, K-half split, 512 threads) into AGPRs
// via hard "a" asm constraints (v_accvgpr_write once; v_accvgpr_read at
// use). The allocator MUST honor asm constraints - no heuristic involved.
// Budget: 192 AGPR + ~50 arch VGPR < 256 regs/wave at 2 waves/SIMD
// (LDS 144.6 KB => 1 WG/CU => 8 waves => 2/SIMD; waves_per_eu(2,2)).

#define NSTEP 2048

typedef _Float16 half_t;
typedef _Float16 half2_t __attribute__((ext_vector_type(2)));

__device__ __forceinline__ float fdot2(half2_t a, half2_t b, float c) {
    return __builtin_amdgcn_fdot2(a, b, c, false);
}

__device__ __forceinline__ unsigned int packh2(float x, float y) {
    union { half2_t h; unsigned int u; } c;
    c.h = half2_t{(half_t)x, (half_t)y};
    return c.u;
}

__device__ __forceinline__ half2_t h2(unsigned int u) {
    union { unsigned int x; half2_t h; } c;
    c.x = u;
    return c.h;
}

union F4H { float4 f; half2_t h[4]; };
union F2H { float2 f; half2_t h[2]; };

__device__ __forceinline__ float tanh_fast(float p) {
    float ex = __expf(2.0f * p);
    return 1.0f - 2.0f / (ex + 1.0f);
}

// ---- AGPR stash machinery: 192 individually-named scalars, hard "a" class.
#define F16(X, A) X(A,0) X(A,1) X(A,2) X(A,3) X(A,4) X(A,5) X(A,6) X(A,7) \
                  X(A,8) X(A,9) X(A,10) X(A,11) X(A,12) X(A,13) X(A,14) X(A,15)
#define DECLAG(A,n) unsigned A##n;
// write pack (woff_+n) of current wsrc_ into AGPR A##n
#define WRAG(A,n) { float2 v2_ = wsrc_[woff_ + n]; \
    unsigned t_ = packh2(v2_.x, v2_.y); \
    asm volatile("v_accvgpr_write_b32 %0, %1" : "=a"(A##n) : "v"(t_)); }
// read AGPR s into VGPR d
#define RD(d, s) asm volatile("v_accvgpr_read_b32 %0, %1" : "=v"(d) : "a"(s));

// R1 step: one float4 of x (4 half2) against C2 packs Cp##s0..s3 and A packs Ap##s0..s3
#define QK4(Cp,Ap,s0,s1,s2,s3,base) { \
    F4H xv_; xv_.f = *(const float4*)(xs + (base) * 8); \
    unsigned u0_,u1_,u2_,u3_,w0_,w1_,w2_,w3_; \
    RD(u0_,Cp##s0) RD(u1_,Cp##s1) RD(u2_,Cp##s2) RD(u3_,Cp##s3) \
    RD(w0_,Ap##s0) RD(w1_,Ap##s1) RD(w2_,Ap##s2) RD(w3_,Ap##s3) \
    aC0 = fdot2(h2(u0_), xv_.h[0], aC0); aA0 = fdot2(h2(w0_), xv_.h[0], aA0); \
    aC1 = fdot2(h2(u1_), xv_.h[1], aC1); aA1 = fdot2(h2(w1_), xv_.h[1], aA1); \
    aC0 = fdot2(h2(u2_), xv_.h[2], aC0); aA0 = fdot2(h2(w2_), xv_.h[2], aA0); \
    aC1 = fdot2(h2(u3_), xv_.h[3], aC1); aA1 = fdot2(h2(w3_), xv_.h[3], aA1); }

// R3 step: one float4 of w against B2 packs Bp##s0..s3
#define PV4(Bp,s0,s1,s2,s3,base) { \
    F4H wv_; wv_.f = *(const float4*)(wsl + (base) * 8); \
    unsigned u0_,u1_,u2_,u3_; \
    RD(u0_,Bp##s0) RD(u1_,Bp##s1) RD(u2_,Bp##s2) RD(u3_,Bp##s3) \
    aX0 = fdot2(h2(u0_), wv_.h[0], aX0); \
    aX1 = fdot2(h2(u1_), wv_.h[1], aX1); \
    aX0 = fdot2(h2(u2_), wv_.h[2], aX0); \
    aX1 = fdot2(h2(u3_), wv_.h[3], aX1); }

// LDS layout (bytes):
//      0: D21T4  [16 j4][256 i][4h]  32768
//  32768: BT4    [16 j4][256 i][4h]  32768
//  65536: CT4    [64 j4][ 64 i][4h]  32768
//  98304: D12T4  [64 j4][ 64 i][4h]  32768
// 131072: DT4    [16 j4][ 64 i][4h]   8192
// 139264: x_h    [256] half            512
// 139776: w_h    [256] half            512
// 140288: d_h    [2][64] half          256
// 140544: red_a  [512] float          2048
// 142592: red_e  [512] float          2048
// total 144640 B
#define LDS_TOTAL 144640

__global__
__attribute__((amdgpu_flat_work_group_size(512, 512)))
__attribute__((amdgpu_waves_per_eu(2, 2)))
void lure_kernel(const float* __restrict__ d_g, const float* __restrict__ x0_g,
                 const float* __restrict__ A_g, const float* __restrict__ B_g,
                 const float* __restrict__ B2_g, const float* __restrict__ C_g,
                 const float* __restrict__ D_g, const float* __restrict__ D12_g,
                 const float* __restrict__ C2_g, const float* __restrict__ D21_g,
                 float* __restrict__ out)
{
    __shared__ __align__(16) char smem[LDS_TOTAL];
    half_t* D21T = (half_t*)(smem + 0);
    half_t* BT   = (half_t*)(smem + 32768);
    half_t* CT   = (half_t*)(smem + 65536);
    half_t* D12T = (half_t*)(smem + 98304);
    half_t* DT   = (half_t*)(smem + 131072);
    half_t* x_h  = (half_t*)(smem + 139264);
    half_t* w_h  = (half_t*)(smem + 139776);
    half_t* d_h  = (half_t*)(smem + 140288);
    float*  red_a= (float*)(smem + 140544);
    float*  red_e= (float*)(smem + 142592);

    const int t = threadIdx.x;
    const int b = blockIdx.x;
    const int i = t & 255;    // output row for w/x phases
    const int g = t >> 8;     // K-half (cols 128g .. 128g+127)
    const int ie = t & 63;    // output row for e phase
    const int sl = t >> 6;    // e-phase K slice (8 slices)

    // ---- AGPR stash: 192 packs = 3 matrices x 64 half2 (K-half = 128 cols)
    F16(DECLAG, c2a_) F16(DECLAG, c2b_) F16(DECLAG, c2c_) F16(DECLAG, c2d_)
    F16(DECLAG, ara_) F16(DECLAG, arb_) F16(DECLAG, arc_) F16(DECLAG, ard_)
    F16(DECLAG, b2a_) F16(DECLAG, b2b_) F16(DECLAG, b2c_) F16(DECLAG, b2d_)
    {
        const float2* wsrc_; int woff_;
        wsrc_ = (const float2*)(C2_g + i * 256 + g * 128);
        woff_ = 0;  F16(WRAG, c2a_)
        woff_ = 16; F16(WRAG, c2b_)
        woff_ = 32; F16(WRAG, c2c_)
        woff_ = 48; F16(WRAG, c2d_)
        wsrc_ = (const float2*)(A_g + i * 256 + g * 128);
        woff_ = 0;  F16(WRAG, ara_)
        woff_ = 16; F16(WRAG, arb_)
        woff_ = 32; F16(WRAG, arc_)
        woff_ = 48; F16(WRAG, ard_)
        wsrc_ = (const float2*)(B2_g + i * 256 + g * 128);
        woff_ = 0;  F16(WRAG, b2a_)
        woff_ = 16; F16(WRAG, b2b_)
        woff_ = 32; F16(WRAG, b2c_)
        woff_ = 48; F16(WRAG, b2d_)
    }

    // ---- one-time: LDS transposed-packed small matrices
    for (int e = t; e < 256 * 64; e += 512) {          // D21 [256][64]
        int r = e >> 6, c = e & 63;
        D21T[((c >> 2) * 256 + r) * 4 + (c & 3)] = (half_t)D21_g[e];
    }
    for (int e = t; e < 256 * 64; e += 512) {          // B [256][64]
        int r = e >> 6, c = e & 63;
        BT[((c >> 2) * 256 + r) * 4 + (c & 3)] = (half_t)B_g[e];
    }
    for (int e = t; e < 64 * 256; e += 512) {          // C [64][256]
        int r = e >> 8, c = e & 255;
        CT[((c >> 2) * 64 + r) * 4 + (c & 3)] = (half_t)C_g[e];
    }
    for (int e = t; e < 64 * 256; e += 512) {          // D12 [64][256]
        int r = e >> 8, c = e & 255;
        D12T[((c >> 2) * 64 + r) * 4 + (c & 3)] = (half_t)D12_g[e];
    }
    for (int e = t; e < 64 * 64; e += 512) {           // D [64][64]
        int r = e >> 6, c = e & 63;
        DT[((c >> 2) * 64 + r) * 4 + (c & 3)] = (half_t)D_g[e];
    }
    // initial state + d_0
    if (t < 256) x_h[t] = (half_t)x0_g[b * 256 + t];
    if (t >= 320 && t < 384) d_h[t - 320] = (half_t)d_g[(b * NSTEP) * 64 + (t - 320)];
    __syncthreads();

    const float* dpre = d_g + (b * NSTEP + 1) * 64 + (t - 320); // wave 5 prefetch ptr
    const int out_e_base = b * (NSTEP * 64);
    const int out_x_base = 256 * NSTEP * 64 + b * 256;
    const int out_w_base = 256 * NSTEP * 64 + 256 * 256 + b * 256;

    int cur = 0; // d ring slot for d_k (== k & 1)
    for (int k = 0; k <= NSTEP; ++k) {
        const bool live = (k < NSTEP);

        // prefetch d_{k+1} (wave 5)
        float dpf = 0.0f;
        if (k < NSTEP - 1 && t >= 320 && t < 384) dpf = *dpre;

        // ---- R1: w_pre partial (C2·x + D21·d) and A·x partial
        float aC0 = 0.f, aC1 = 0.f, aA0 = 0.f, aA1 = 0.f;
        if (live) {
            const half_t* xs = x_h + (g << 7);
            QK4(c2a_,ara_, 0,1,2,3,    0)
            QK4(c2a_,ara_, 4,5,6,7,    1)
            QK4(c2a_,ara_, 8,9,10,11,  2)
            QK4(c2a_,ara_, 12,13,14,15,3)
            QK4(c2b_,arb_, 0,1,2,3,    4)
            QK4(c2b_,arb_, 4,5,6,7,    5)
            QK4(c2b_,arb_, 8,9,10,11,  6)
            QK4(c2b_,arb_, 12,13,14,15,7)
            QK4(c2c_,arc_, 0,1,2,3,    8)
            QK4(c2c_,arc_, 4,5,6,7,    9)
            QK4(c2c_,arc_, 8,9,10,11, 10)
            QK4(c2c_,arc_, 12,13,14,15,11)
            QK4(c2d_,ard_, 0,1,2,3,   12)
            QK4(c2d_,ard_, 4,5,6,7,   13)
            QK4(c2d_,ard_, 8,9,10,11, 14)
            QK4(c2d_,ard_, 12,13,14,15,15)
#pragma unroll
            for (int qq = 0; qq < 8; ++qq) {
                int j4 = (g << 3) + qq;
                F2H m;  m.f  = *(const float2*)(D21T + (j4 * 256 + i) * 4);
                F2H dv; dv.f = *(const float2*)(d_h + cur * 64 + (j4 << 2));
                aC0 = fdot2(m.h[0], dv.h[0], aC0);
                aC1 = fdot2(m.h[1], dv.h[1], aC1);
            }
            red_a[t] = aC0 + aC1;
        }

        // ---- E phase for step k-1: e = C·x_k + D12·w_{k-1} + D·d_{k-1}
        if (k > 0) {
            float aE0 = 0.f, aE1 = 0.f;
#pragma unroll
            for (int qq = 0; qq < 8; ++qq) {
                int j4 = (sl << 3) + qq;
                F2H m;  m.f  = *(const float2*)(CT + (j4 * 64 + ie) * 4);
                F2H xv; xv.f = *(const float2*)(x_h + (j4 << 2));
                aE0 = fdot2(m.h[0], xv.h[0], aE0);
                aE1 = fdot2(m.h[1], xv.h[1], aE1);
            }
#pragma unroll
            for (int qq = 0; qq < 8; ++qq) {
                int j4 = (sl << 3) + qq;
                F2H m;  m.f  = *(const float2*)(D12T + (j4 * 64 + ie) * 4);
                F2H wv; wv.f = *(const float2*)(w_h + (j4 << 2));
                aE0 = fdot2(m.h[0], wv.h[0], aE0);
                aE1 = fdot2(m.h[1], wv.h[1], aE1);
            }
#pragma unroll
            for (int qq = 0; qq < 2; ++qq) {
                int j4 = (sl << 1) + qq;
                F2H m;  m.f  = *(const float2*)(DT + (j4 * 64 + ie) * 4);
                F2H dv; dv.f = *(const float2*)(d_h + (cur ^ 1) * 64 + (j4 << 2));
                aE0 = fdot2(m.h[0], dv.h[0], aE0);
                aE1 = fdot2(m.h[1], dv.h[1], aE1);
            }
            red_e[t] = aE0 + aE1;
        }
        __syncthreads(); // A

        // ---- R2: tanh+w (waves 0-3) | e-reduce+store (wave 4) | d_h fill (wave 5)
        if (t < 256) {
            if (live) {
                float p = red_a[t] + red_a[t + 256];
                float wv = tanh_fast(p);
                w_h[t] = (half_t)wv;
                if (k == NSTEP - 1) out[out_w_base + t] = wv;
            }
        } else if (t < 320) {
            if (k > 0) {
                float ev = red_e[ie] + red_e[64 + ie] + red_e[128 + ie] + red_e[192 + ie]
                         + red_e[256 + ie] + red_e[320 + ie] + red_e[384 + ie] + red_e[448 + ie];
                out[out_e_base + (k - 1) * 64 + ie] = ev;
            }
        } else if (t < 384) {
            if (k < NSTEP - 1) d_h[(cur ^ 1) * 64 + (t - 320)] = (half_t)dpf;
        }
        __syncthreads(); // B

        // ---- R3: x' partial (A·x done) + B2·w + B·d
        if (live) {
            float aX0 = aA0, aX1 = aA1;
            const half_t* wsl = w_h + (g << 7);
            PV4(b2a_, 0,1,2,3,    0)
            PV4(b2a_, 4,5,6,7,    1)
            PV4(b2a_, 8,9,10,11,  2)
            PV4(b2a_, 12,13,14,15,3)
            PV4(b2b_, 0,1,2,3,    4)
            PV4(b2b_, 4,5,6,7,    5)
            PV4(b2b_, 8,9,10,11,  6)
            PV4(b2b_, 12,13,14,15,7)
            PV4(b2c_, 0,1,2,3,    8)
            PV4(b2c_, 4,5,6,7,    9)
            PV4(b2c_, 8,9,10,11, 10)
            PV4(b2c_, 12,13,14,15,11)
            PV4(b2d_, 0,1,2,3,   12)
            PV4(b2d_, 4,5,6,7,   13)
            PV4(b2d_, 8,9,10,11, 14)
            PV4(b2d_, 12,13,14,15,15)
#pragma unroll
            for (int qq = 0; qq < 8; ++qq) {
                int j4 = (g << 3) + qq;
                F2H m;  m.f  = *(const float2*)(BT + (j4 * 256 + i) * 4);
                F2H dv; dv.f = *(const float2*)(d_h + cur * 64 + (j4 << 2));
                aX0 = fdot2(m.h[0], dv.h[0], aX0);
                aX1 = fdot2(m.h[1], dv.h[1], aX1);
            }
            red_a[t] = aX0 + aX1;
        }
        __syncthreads(); // C

        // ---- R4: x update
        if (live && t < 256) {
            float xv = red_a[t] + red_a[t + 256];
            x_h[t] = (half_t)xv;
            if (k == NSTEP - 1) out[out_x_base + t] = xv;
        }
        dpre += 64;
        cur ^= 1;
        __syncthreads(); // D
    }
}

extern "C" void kernel_launch(void* const* d_in, const int* in_sizes, int n_in,
                              void* d_out, int out_size, void* d_ws, size_t ws_size,
                              hipStream_t stream) {
    (void)in_sizes; (void)n_in; (void)out_size; (void)d_ws; (void)ws_size;
    const float* d_  = (const float*)d_in[0];
    const float* x0  = (const float*)d_in[1];
    const float* A   = (const float*)d_in[2];
    const float* B   = (const float*)d_in[3];
    const float* B2  = (const float*)d_in[4];
    const float* C   = (const float*)d_in[5];
    const float* D   = (const float*)d_in[6];
    const float* D12 = (const float*)d_in[7];
    const float* C2  = (const float*)d_in[8];
    const float* D21 = (const float*)d_in[9];
    float* out = (float*)d_out;

    hipLaunchKernelGGL(lure_kernel, dim3(256), dim3(512), 0, stream,
                       d_, x0, A, B, B2, C, D, D12, C2, D21, out);
}